// Round 8
// baseline (1568.623 us; speedup 1.0000x reference)
//
#include <hip/hip_runtime.h>

#define BATCH 64
#define TIN   49
#define NB    24
#define HID   384
#define SOUT  10
#define NGATE 5

typedef __attribute__((ext_vector_type(4))) float f32x4;
typedef __attribute__((ext_vector_type(8))) short short8v;

__device__ __forceinline__ unsigned short f2bf(float f) {
    union { float f; unsigned u; } v; v.f = f;
    unsigned r = v.u + 0x7fffu + ((v.u >> 16) & 1u);   // round-nearest-even
    return (unsigned short)(r >> 16);
}
__device__ __forceinline__ float bf2f(unsigned short h) {
    union { unsigned u; float f; } v; v.u = ((unsigned)h) << 16; return v.f;
}

#define NW2_BLK 25920   // 48 cells * 5 gates * 3 mats * 36 (6 kb x 6 cb) tiles
#define NP_BLK  23040
#define NM_BLK  576
#define NITEMS  5760    // 480 cell-instances x 12 col-tiles
#define PGRID   256     // 1 block/CU (145 KB LDS), co-resident

// ---------------------------------------------------------------------------
// Fused prologue: pack_w (LDS-transposed) + pack_p + init_means.
// wpack layout (short8 units): [(cell*12+t32)*5+g][kc=36][pair=2][lane=64]
//   kc = m*12 + kh*6 + j ; elem jj: B[k][col], k within source m,
//   col = t32*32 + pair*16 + (lane&15).
// ---------------------------------------------------------------------------
__global__ __launch_bounds__(256) void prologue_kernel(
    const float* __restrict__ U, const float* __restrict__ Wt,
    const float* __restrict__ Ws, const float* __restrict__ p,
    const float* __restrict__ hid, const float* __restrict__ cel,
    const float* __restrict__ gt,
    unsigned short* __restrict__ wpack, unsigned short* __restrict__ pb,
    unsigned short* __restrict__ hp_b, float* __restrict__ cp_f)
{
    __shared__ unsigned short tile[64][68];
    int bx = blockIdx.x;
    if (bx < NW2_BLK) {
        int q = bx;
        int cb = q % 6; q /= 6;
        int kb = q % 6; q /= 6;
        int m  = q % 3; q /= 3;
        int g  = q % 5; q /= 5;
        int cell = q;                                  // 0..47 (r*NB+n)
        const float* W = (m == 0) ? U : (m == 1) ? Wt : Ws;
        const float* src = W + ((size_t)(cell * NGATE + g) * HID + kb * 64) * HID + cb * 64;
        int t = threadIdx.x;
        int kr = t >> 4, c4 = (t & 15) * 4;
#pragma unroll
        for (int i = 0; i < 4; ++i) {
            float4 v = *(const float4*)(src + (size_t)(kr + 16 * i) * HID + c4);
            tile[kr + 16 * i][c4 + 0] = f2bf(v.x);
            tile[kr + 16 * i][c4 + 1] = f2bf(v.y);
            tile[kr + 16 * i][c4 + 2] = f2bf(v.z);
            tile[kr + 16 * i][c4 + 3] = f2bf(v.w);
        }
        __syncthreads();
#pragma unroll
        for (int ii = 0; ii < 2; ++ii) {
            int e = t + 256 * ii;
            int lane = e & 63; int qq = e >> 6;        // 0..7
            int pair = qq & 1, kc2 = (qq >> 1) & 1, t2 = qq >> 2;
            int kl = kc2 * 32 + (lane >> 4) * 8;
            int cl = t2 * 32 + pair * 16 + (lane & 15);
            unsigned short o[8];
#pragma unroll
            for (int jj = 0; jj < 8; ++jj) o[jj] = tile[kl + jj][cl];
            int t32 = cb * 2 + t2;
            int kc  = m * 12 + kb * 2 + kc2;
            size_t dst = ((size_t)((cell * 12 + t32) * NGATE + g) * (36 * 2)
                          + kc * 2 + pair) * 64 + lane;
            *(short8v*)(wpack + dst * 8) = *(const short8v*)o;
        }
    } else if (bx < NW2_BLK + NP_BLK) {
        // p f32 [B][SOUT][NB][H] -> bf16 [SOUT][NB][B][H]
        size_t idx = (size_t)(bx - NW2_BLK) * 256 + threadIdx.x;  // 5,898,240
        int h = (int)(idx % HID);
        size_t q = idx / HID;
        int b = (int)(q % BATCH); q /= BATCH;
        int n = (int)(q % NB); q /= NB;
        int f = (int)q;
        pb[idx] = f2bf(p[((size_t)(b * SOUT + f) * NB + n) * HID + h]);
    } else {
        // temporal means -> hp (bf16) + cp (f32), layout [r][n][b][h]
        int idx = (bx - NW2_BLK - NP_BLK) * 256 + threadIdx.x;    // 147,456
        const int total4 = NB * BATCH * HID / 4;
        if (idx >= total4) return;
        const int H4 = HID / 4;
        int h = (idx % H4) * 4;
        int b = (idx / H4) % BATCH;
        int n = idx / (H4 * BATCH);
        const int fs4 = NB * HID / 4;
        const float4* ph = (const float4*)(hid + ((size_t)b * TIN * NB + n) * HID + h);
        const float4* pc = (const float4*)(cel + ((size_t)b * TIN * NB + n) * HID + h);
        float sh[4] = {0,0,0,0}, sc[4] = {0,0,0,0};
        for (int t = 0; t < TIN; ++t) {
            float4 vh = ph[(size_t)t * fs4];
            float4 vc = pc[(size_t)t * fs4];
            sh[0] += vh.x; sh[1] += vh.y; sh[2] += vh.z; sh[3] += vh.w;
            sc[0] += vc.x; sc[1] += vc.y; sc[2] += vc.z; sc[3] += vc.w;
        }
        float4 g4 = *(const float4*)(gt + ((size_t)b * NB + n) * HID + h);
        const float* g_ = (const float*)&g4;
        unsigned short o0[4], o1[4];
        float c0[4];
#pragma unroll
        for (int j = 0; j < 4; ++j) {
            o0[j] = f2bf(sh[j] / TIN);
            o1[j] = f2bf((g_[j] + sh[j]) / (TIN + 1));
            c0[j] = sc[j] / TIN;
        }
        size_t base = (size_t)idx * 4;
        const size_t tot = (size_t)NB * BATCH * HID;
        *(uint2*)(hp_b + base)       = *(const uint2*)o0;
        *(uint2*)(hp_b + tot + base) = *(const uint2*)o1;
        *(float4*)(cp_f + base)       = make_float4(c0[0], c0[1], c0[2], c0[3]);
        *(float4*)(cp_f + tot + base) = make_float4(c0[0], c0[1], c0[2], c0[3]);
    }
}

// spatial boundary: mean over bones of the r=0 init states
__global__ void init_bounds_kernel(const unsigned short* __restrict__ hp_b,
                                   const float* __restrict__ cp_f,
                                   unsigned short* __restrict__ bh_b,
                                   float* __restrict__ bc_f) {
    int idx = blockIdx.x * blockDim.x + threadIdx.x;       // BATCH*HID
    if (idx >= BATCH * HID) return;
    float sh = 0.f, sc = 0.f;
    for (int n = 0; n < NB; ++n) {
        sh += bf2f(hp_b[(size_t)n * BATCH * HID + idx]);
        sc += cp_f[(size_t)n * BATCH * HID + idx];
    }
    bh_b[idx] = f2bf(sh / NB);
    bc_f[idx] = sc / NB;
}

__global__ void reset_kernel(int* done, int* tick) {
    int i = blockIdx.x * blockDim.x + threadIdx.x;
    if (i < 2 * NB * SOUT) done[i] = 0;
    if (i == 0) *tick = 0;
}

// ---------------------------------------------------------------------------
// Persistent dataflow kernel: round-7 block structure (LDS-shared A dbuf,
// reg-staged pipeline, 32-col tiles) inside the ticket framework.
// 256 blocks x 640 threads (10 waves: gate=wv%5, kh=wv/5). No dispatch
// boundaries -> no cache flushes -> cross-stage weight re-reads (90% overlap
// between consecutive stages) hit L2/L3 instead of HBM.
// Gate exchange is two-pass in gl[5][64][35] (kh=1 writes, kh=0 adds) so
// A-dbuf(100KB) + gl(45KB) fit in 160 KB LDS.
// ---------------------------------------------------------------------------
__global__ __launch_bounds__(640) void persist_kernel(
    const unsigned short* __restrict__ pb,
    const unsigned short* __restrict__ wpack,
    const float* __restrict__ bias,
    const unsigned short* __restrict__ hp_b,
    const float* __restrict__ cp_f,
    const unsigned short* __restrict__ bh_b,
    const float* __restrict__ bc_f,
    unsigned short* __restrict__ h_st,   // [2][NB][SOUT][64][384] bf16
    float* __restrict__ c_st,            // same shape f32
    float* __restrict__ out,
    int* __restrict__ done,              // [2*NB*SOUT]
    int* __restrict__ tick)
{
    const int wv   = threadIdx.x >> 6;
    const int gate = wv % NGATE;
    const int kh   = wv / NGATE;
    const int lane = threadIdx.x & 63;
    const int S = BATCH * HID;

    __shared__ unsigned short Ab[2][64][392];   // padded -> 2-way banks
    __shared__ float gl[NGATE][64][35];
    __shared__ int s_tkt;

    for (;;) {
        __syncthreads();
        if (threadIdx.x == 0)
            s_tkt = __hip_atomic_fetch_add(tick, 1, __ATOMIC_RELAXED,
                                           __HIP_MEMORY_SCOPE_AGENT);
        __syncthreads();
        const int T = s_tkt;
        if (T >= NITEMS) return;

        // ---- decode ticket -> (r, n, f, t) in topo order (12 tiles/cell)
        int rem = T, r = 0, lo = 0, d = 0;
        for (int s = 0;; ++s) {
            d = s >> 1; r = s & 1;
            lo = d - (SOUT - 1); if (lo < 0) lo = 0;
            int hi = (d < NB - 1) ? d : NB - 1;
            int c = (hi - lo + 1) * 12;
            if (rem < c) break;
            rem -= c;
        }
        const int n = lo + rem / 12;
        const int t = rem % 12;
        const int f = d - n;
        const int cell = r * NB + n;
        const int ci = cell * SOUT + f;

        const short8v* wp = (const short8v*)wpack
            + (size_t)((cell * 12 + t) * NGATE + gate) * (36 * 2 * 64);

        // ---- prefetch-touch this item's weights while deps resolve
        {
            const uint4* wt = (const uint4*)(wp + (size_t)(kh * 6 * 2) * 64 + lane);
            unsigned dx = 0, dy = 0, dz = 0, dw = 0;
#pragma unroll
            for (int s = 0; s < 36; ++s) {      // 3 mats x 6 kc x 2 pair
                int m = s / 12, j = s % 12;
                uint4 v = wt[((size_t)m * 24 + j) * 64];
                dx ^= v.x; dy ^= v.y; dz ^= v.z; dw ^= v.w;
            }
            asm volatile("" :: "v"(dx), "v"(dy), "v"(dz), "v"(dw) : "memory");
        }

        // ---- dependency wait: single-thread relaxed polling + final acquire
        {
            int dep0 = -1, dep1 = -1, dep2 = -1;
            if (r == 0) {
                if (f > 0) dep0 = n * SOUT + f - 1;
                if (n > 0) dep1 = (n - 1) * SOUT + f;
            } else {
                dep0 = n * SOUT + f;
                if (f > 0) dep1 = (NB + n) * SOUT + f - 1;
                if (n > 0) dep2 = (NB + n - 1) * SOUT + f;
            }
            if (threadIdx.x == 0) {
                int deps[3] = { dep0, dep1, dep2 };
#pragma unroll
                for (int i = 0; i < 3; ++i) {
                    int dp = deps[i];
                    if (dp < 0) continue;
                    while (__hip_atomic_load(done + dp, __ATOMIC_RELAXED,
                                             __HIP_MEMORY_SCOPE_AGENT) < 12)
                        __builtin_amdgcn_s_sleep(8);
                    int z = __hip_atomic_load(done + dp, __ATOMIC_ACQUIRE,
                                              __HIP_MEMORY_SCOPE_AGENT);
                    asm volatile("" :: "v"(z));
                }
            }
            __syncthreads();
        }

        // ---- operand base pointers (deps now satisfied)
        const unsigned short *xb, *htb, *hsb;
        const float *ctb, *csb;
        if (r == 0) {
            xb  = pb + (size_t)(f * NB + n) * S;
            htb = f ? h_st + (size_t)(n * SOUT + f - 1) * S : hp_b + (size_t)n * S;
            hsb = n ? h_st + (size_t)((n - 1) * SOUT + f) * S : bh_b;
            ctb = f ? c_st + (size_t)(n * SOUT + f - 1) * S : cp_f + (size_t)n * S;
            csb = n ? c_st + (size_t)((n - 1) * SOUT + f) * S : bc_f;
        } else {
            xb  = h_st + (size_t)(n * SOUT + f) * S;        // h0 of this cell
            htb = f ? h_st + (size_t)((NB + n) * SOUT + f - 1) * S
                    : hp_b + (size_t)(NB + n) * S;
            hsb = n ? h_st + (size_t)((NB + n - 1) * SOUT + f) * S : bh_b;
            ctb = f ? c_st + (size_t)((NB + n) * SOUT + f - 1) * S
                    : cp_f + (size_t)(NB + n) * S;
            csb = n ? c_st + (size_t)((NB + n - 1) * SOUT + f) * S : bc_f;
        }

        // ---- hoist epilogue cell-state loads (latency hides under MFMA)
        const int eb = threadIdx.x & 63;
        const int ecq = (threadIdx.x >> 6) & 3;
        float4 cth[2], csh[2];
        if (threadIdx.x < 256) {
#pragma unroll
            for (int h = 0; h < 2; ++h) {
                int colg = t * 32 + h * 16 + ecq * 4;
                cth[h] = *(const float4*)(ctb + (size_t)eb * HID + colg);
                csh[h] = *(const float4*)(csb + (size_t)eb * HID + colg);
            }
        }

        // ---- staging machinery: 64x384 bf16 = 3072 16B-chunks, 640 threads
        uint4 streg[5];
        auto STAGE_LOAD = [&](const unsigned short* src) {
#pragma unroll
            for (int i = 0; i < 5; ++i) {
                int c = (int)threadIdx.x + i * 640;
                if (i < 4 || c < 3072) {
                    int row = c / 48, cc = c - row * 48;
                    streg[i] = *(const uint4*)(src + (size_t)row * HID + cc * 8);
                }
            }
        };
        auto STAGE_WRITE = [&](int buf) {
#pragma unroll
            for (int i = 0; i < 5; ++i) {
                int c = (int)threadIdx.x + i * 640;
                if (i < 4 || c < 3072) {
                    int row = c / 48, cc = c - row * 48;
                    *(uint4*)&Ab[buf][row][cc * 8] = streg[i];
                }
            }
        };

        f32x4 acc[2][4];
#pragma unroll
        for (int pr = 0; pr < 2; ++pr)
#pragma unroll
            for (int q = 0; q < 4; ++q) acc[pr][q] = (f32x4){0, 0, 0, 0};

        const int arow = lane & 15;
        const int akg  = (lane >> 4) * 8;

        auto COMPUTE = [&](int m, int buf) {
            const short8v* wbm = wp + (size_t)((m * 12 + kh * 6) * 2) * 64 + lane;
            short8v bufB[3][2];
#pragma unroll
            for (int j = 0; j < 3; ++j) {
                bufB[j][0] = wbm[(size_t)j * 128];
                bufB[j][1] = wbm[(size_t)j * 128 + 64];
            }
#pragma unroll
            for (int j = 0; j < 6; ++j) {
                const int koff = kh * 192 + j * 32 + akg;
                short8v a[4];
#pragma unroll
                for (int q = 0; q < 4; ++q)
                    a[q] = *(const short8v*)&Ab[buf][arow + q * 16][koff];
                const int sl = j % 3;
#pragma unroll
                for (int q = 0; q < 4; ++q) {
                    acc[0][q] = __builtin_amdgcn_mfma_f32_16x16x32_bf16(a[q], bufB[sl][0], acc[0][q], 0, 0, 0);
                    acc[1][q] = __builtin_amdgcn_mfma_f32_16x16x32_bf16(a[q], bufB[sl][1], acc[1][q], 0, 0, 0);
                }
                if (j < 3) {
                    bufB[sl][0] = wbm[(size_t)(j + 3) * 128];
                    bufB[sl][1] = wbm[(size_t)(j + 3) * 128 + 64];
                }
            }
        };

        // ---- pipeline
        STAGE_LOAD(xb);
        STAGE_WRITE(0);
        __syncthreads();

        STAGE_LOAD(htb);
        COMPUTE(0, 0);
        __syncthreads();
        STAGE_WRITE(1);
        __syncthreads();

        STAGE_LOAD(hsb);
        COMPUTE(1, 1);
        __syncthreads();
        STAGE_WRITE(0);
        __syncthreads();

        COMPUTE(2, 0);

        // ---- two-pass gate exchange: kh=1 writes, kh=0 accumulates
        if (kh == 1) {
#pragma unroll
            for (int pr = 0; pr < 2; ++pr)
#pragma unroll
                for (int q = 0; q < 4; ++q)
#pragma unroll
                    for (int i = 0; i < 4; ++i)
                        gl[gate][q * 16 + (lane >> 4) * 4 + i][pr * 16 + (lane & 15)]
                            = acc[pr][q][i];
        }
        __syncthreads();
        if (kh == 0) {
#pragma unroll
            for (int pr = 0; pr < 2; ++pr)
#pragma unroll
                for (int q = 0; q < 4; ++q)
#pragma unroll
                    for (int i = 0; i < 4; ++i)
                        gl[gate][q * 16 + (lane >> 4) * 4 + i][pr * 16 + (lane & 15)]
                            += acc[pr][q][i];
        }
        __syncthreads();

        // ---- fused epilogue (256 threads)
        if (threadIdx.x < 256) {
            size_t dbase = (size_t)ci * S + (size_t)eb * HID;
            const float* bbase = bias + (size_t)cell * NGATE * HID;
#pragma unroll
            for (int h = 0; h < 2; ++h) {
                int cloc = h * 16 + ecq * 4;
                int colg = t * 32 + cloc;
                const float* ct_ = (const float*)&cth[h];
                const float* cs_ = (const float*)&csh[h];
                float hv4[4], ch4[4];
                unsigned short hb4[4];
#pragma unroll
                for (int cc = 0; cc < 4; ++cc) {
                    float gi  = gl[0][eb][cloc + cc] + bbase[0 * HID + colg + cc];
                    float gfs = gl[1][eb][cloc + cc] + bbase[1 * HID + colg + cc];
                    float gft = gl[2][eb][cloc + cc] + bbase[2 * HID + colg + cc];
                    float go  = gl[3][eb][cloc + cc] + bbase[3 * HID + colg + cc];
                    float gc  = gl[4][eb][cloc + cc] + bbase[4 * HID + colg + cc];
                    float i_n = 1.f / (1.f + __expf(-gi));
                    float f_s = 1.f / (1.f + __expf(-gfs));
                    float f_t = 1.f / (1.f + __expf(-gft));
                    float o_n = 1.f / (1.f + __expf(-go));
                    float c_n = tanhf(gc);
                    float ch  = i_n * c_n + f_t * ct_[cc] + f_s * cs_[cc];
                    float hv  = o_n * tanhf(ch);
                    hv4[cc] = hv; ch4[cc] = ch; hb4[cc] = f2bf(hv);
                }
                *(uint2*)(h_st + dbase + colg) = *(const uint2*)hb4;
                *(float4*)(c_st + dbase + colg) = make_float4(ch4[0], ch4[1], ch4[2], ch4[3]);
                if (r == 1) {
                    size_t o = ((size_t)(eb * SOUT + f) * NB + n) * HID + colg;
                    *(float4*)(out + o) = make_float4(hv4[0], hv4[1], hv4[2], hv4[3]);
                    *(float4*)(out + (size_t)BATCH * SOUT * NB * HID + o)
                        = make_float4(ch4[0], ch4[1], ch4[2], ch4[3]);
                }
            }
        }
        __syncthreads();
        if (threadIdx.x == 0)
            __hip_atomic_fetch_add(done + ci, 1, __ATOMIC_RELEASE,
                                   __HIP_MEMORY_SCOPE_AGENT);
    }
}

// ---------------------------------------------------------------------------
extern "C" void kernel_launch(void* const* d_in, const int* in_sizes, int n_in,
                              void* d_out, int out_size, void* d_ws, size_t ws_size,
                              hipStream_t stream) {
    const float* hid  = (const float*)d_in[0];
    const float* cel  = (const float*)d_in[1];
    const float* gt   = (const float*)d_in[2];
    // d_in[3] global_s_state: unused by the reference
    const float* p    = (const float*)d_in[4];
    const float* U    = (const float*)d_in[5];
    const float* Wt   = (const float*)d_in[6];
    const float* Ws   = (const float*)d_in[7];
    const float* bias = (const float*)d_in[8];
    float* out = (float*)d_out;

    char* cur_ = (char*)d_ws;
    auto carve = [&](size_t bytes) -> void* {
        void* r = cur_; cur_ += (bytes + 255) & ~(size_t)255; return r;
    };
    const size_t NPBH = (size_t)NB * BATCH * HID;
    unsigned short* wpack = (unsigned short*)carve((size_t)13271040 * 16); // 212 MB
    unsigned short* pb    = (unsigned short*)carve((size_t)SOUT * NB * BATCH * HID * 2);
    unsigned short* hp_b  = (unsigned short*)carve(2 * NPBH * 2);
    float*          cp_f  = (float*)carve(2 * NPBH * 4);
    unsigned short* bh_b  = (unsigned short*)carve((size_t)BATCH * HID * 2);
    float*          bc_f  = (float*)carve((size_t)BATCH * HID * 4);
    unsigned short* h_st  = (unsigned short*)carve((size_t)2 * NB * SOUT * BATCH * HID * 2);
    float*          c_st  = (float*)carve((size_t)2 * NB * SOUT * BATCH * HID * 4);
    int*            done  = (int*)carve(2 * NB * SOUT * sizeof(int));
    int*            tick  = (int*)carve(256);   // own cacheline

    reset_kernel<<<2, 256, 0, stream>>>(done, tick);
    prologue_kernel<<<NW2_BLK + NP_BLK + NM_BLK, 256, 0, stream>>>(
        U, Wt, Ws, p, hid, cel, gt, wpack, pb, hp_b, cp_f);
    init_bounds_kernel<<<(BATCH * HID + 255) / 256, 256, 0, stream>>>(
        hp_b, cp_f, bh_b, bc_f);
    persist_kernel<<<PGRID, 640, 0, stream>>>(
        pb, wpack, bias, hp_b, cp_f, bh_b, bc_f,
        h_st, c_st, out, done, tick);
}